// Round 2
// baseline (1579.604 us; speedup 1.0000x reference)
//
#include <hip/hip_runtime.h>
#include <hip/hip_fp16.h>

// ---------------------------------------------------------------------------
// MMoE extract-net fused kernel, MI355X (gfx950).
// fp16 hi/lo split (3-pass MFMA ~= fp32 accuracy), transposed formulation
// (batch = MFMA column) so h1/h2 chain in registers via shfl_xor(32).
// R2: 13 waves/block (12 experts + 1 gate wave), in-block gated combine via
// LDS-aliased fp32 accumulator + ds_add atomics. No output scratch.
// ---------------------------------------------------------------------------

#define B_TOT   65536
#define IN_DIM  256
#define HD      64
#define NE      12
// ws fragment region layout, in 16-byte units:
//  A1: [e:12][rt:2][kt:16][hl:2][lane:64]   base 0      (12*4096 units)
//  A2: [e:12][rt:2][kt:4 ][hl:2][lane:64]   base 49152  (12*1024)
//  A3: same as A2                            base 61440  (12*1024)
//  AG: [kt:16][hl:2][lane:64]                base 73728  (2048)
#define U_A2 49152
#define U_A3 61440
#define U_AG 73728
#define FRAG_BYTES (75776*16)   // 1,212,416 bytes

typedef _Float16 half8  __attribute__((ext_vector_type(8)));
typedef float    f32x16 __attribute__((ext_vector_type(16)));
typedef float    f32x4  __attribute__((ext_vector_type(4)));
typedef unsigned u32x4  __attribute__((ext_vector_type(4)));

__device__ __forceinline__ unsigned short f2h(float x){
  return __builtin_bit_cast(unsigned short, (_Float16)x);
}
__device__ __forceinline__ float h2f(unsigned short u){
  return (float)__builtin_bit_cast(_Float16, u);
}
__device__ __forceinline__ void split2(float x, unsigned short& h, unsigned short& l){
  h = f2h(x); l = f2h(x - h2f(h));
}
__device__ __forceinline__ half8 FRG(u32x4 u){ return __builtin_bit_cast(half8, u); }
__device__ __forceinline__ f32x16 MF(half8 a, half8 b, f32x16 c){
  return __builtin_amdgcn_mfma_f32_32x32x16_f16(a, b, c, 0, 0, 0);
}
__device__ __forceinline__ f32x16 Z16(){
  f32x16 z;
#pragma unroll
  for (int i=0;i<16;i++) z[i]=0.f;
  return z;
}
// swizzled LDS read of 8 consecutive fp16 of row `row` at byte col offset kb
__device__ __forceinline__ u32x4 lds16(const short* base, int row, int kb){
  return *(const u32x4*)((const char*)base + row*512 + (kb ^ ((row&7)<<4)));
}

// ---------------------------------------------------------------------------
// K0: pre-split weights into hi/lo fp16 MFMA A-fragment layout.
// A-frag (32x32x16): lane holds row=(lane&31), k=(lane>>5)*8 + j, j=0..7.
// ---------------------------------------------------------------------------
__global__ __launch_bounds__(256) void prep(
    const float* __restrict__ Wt1, const float* __restrict__ Ws1,
    const float* __restrict__ Wt2, const float* __restrict__ Ws2,
    const float* __restrict__ Wt3, const float* __restrict__ Ws3,
    const float* __restrict__ Wg,  u32x4* __restrict__ fr){
  int id = blockIdx.x*256 + threadIdx.x;
  if (id >= 37888) return;
  int lane = id & 63;
  int kq   = lane >> 5;
  int row  = lane & 31;
  float v[8];
  unsigned ubase;
  if (id < 24576){                                   // A1 = W1^T  [h][k=in]
    int r = id >> 6; int kt = r & 15; int rt = (r>>4)&1; int e = r>>5;
    const float* W = (e<8) ? (Wt1 + (size_t)e*(IN_DIM*HD))
                           : (Ws1 + (size_t)(e-8)*(IN_DIM*HD));
    int h = rt*32 + row;
#pragma unroll
    for (int j=0;j<8;j++){ int k = kt*16 + kq*8 + j; v[j] = W[k*HD + h]; }
    ubase = (unsigned)(e*4096 + ((rt*16+kt)*2)*64 + lane);
  } else if (id < 30720){                            // A2 = W2^T  [h2][k=h1]
    int r = (id-24576) >> 6; int kt = r & 3; int rt = (r>>2)&1; int e = r>>3;
    const float* W = (e<8) ? (Wt2 + (size_t)e*(HD*HD))
                           : (Ws2 + (size_t)(e-8)*(HD*HD));
    int h = rt*32 + row;
#pragma unroll
    for (int j=0;j<8;j++){ int k = kt*16 + kq*8 + j; v[j] = W[k*HD + h]; }
    ubase = (unsigned)(U_A2 + e*1024 + ((rt*4+kt)*2)*64 + lane);
  } else if (id < 36864){                            // A3 = W3^T  [o][k=h2]
    int r = (id-30720) >> 6; int kt = r & 3; int rt = (r>>2)&1; int e = r>>3;
    const float* W = (e<8) ? (Wt3 + (size_t)e*(HD*HD))
                           : (Ws3 + (size_t)(e-8)*(HD*HD));
    int h = rt*32 + row;
#pragma unroll
    for (int j=0;j<8;j++){ int k = kt*16 + kq*8 + j; v[j] = W[k*HD + h]; }
    ubase = (unsigned)(U_A3 + e*1024 + ((rt*4+kt)*2)*64 + lane);
  } else {                                           // AG = Wg^T padded to 32 rows
    int r = (id-36864) >> 6; int kt = r;
    int g = row;
#pragma unroll
    for (int j=0;j<8;j++){
      int k = kt*16 + kq*8 + j;
      v[j] = (g < 16) ? Wg[(size_t)(g>>3)*(IN_DIM*8) + k*8 + (g&7)] : 0.f;
    }
    ubase = (unsigned)(U_AG + (kt*2)*64 + lane);
  }
  u32x4 uh, ul;
#pragma unroll
  for (int p=0;p<4;p++){
    unsigned short h0,l0,h1,l1;
    split2(v[2*p],h0,l0); split2(v[2*p+1],h1,l1);
    uh[p] = (unsigned)h0 | ((unsigned)h1<<16);
    ul[p] = (unsigned)l0 | ((unsigned)l1<<16);
  }
  fr[ubase]     = uh;
  fr[ubase+64]  = ul;
}

// ---------------------------------------------------------------------------
// epilogue (layers 1/2): bias + relu + fp16 hi/lo split, packed as u32 pairs.
// C/D layout: col=lane&31, row=(j&3)+8*(j>>2)+4*hi  (+32*rt)
__device__ __forceinline__ void epi12(const f32x16& A, const float* bp, int rt, int hi,
                                      unsigned* oh, unsigned* ol){
#pragma unroll
  for (int p=0;p<8;p++){
    const int j0=2*p, j1=2*p+1;
    float v0 = A[j0] + bp[rt*32 + 8*(j0>>2) + 4*hi + (j0&3)];
    float v1 = A[j1] + bp[rt*32 + 8*(j1>>2) + 4*hi + (j1&3)];
    v0 = fmaxf(v0, 0.f); v1 = fmaxf(v1, 0.f);
    unsigned short h0,l0,h1,l1;
    split2(v0,h0,l0); split2(v1,h1,l1);
    oh[p] = (unsigned)h0 | ((unsigned)h1<<16);
    ol[p] = (unsigned)l0 | ((unsigned)l1<<16);
  }
}

// Build B-frag (k=16kt+8*hi + 0..7 of h-dim) from packed C/D pairs via
// half-wave exchange. pk = 8 u32 pairs of one (rt,ct) tile; kl = kt&1.
__device__ __forceinline__ half8 bfrag(const unsigned* pk, int kl, int hi){
  unsigned p0 = pk[4*kl+0], p1 = pk[4*kl+1], p2 = pk[4*kl+2], p3 = pk[4*kl+3];
  unsigned q0 = (unsigned)__shfl_xor((int)p0, 32, 64);
  unsigned q1 = (unsigned)__shfl_xor((int)p1, 32, 64);
  unsigned q2 = (unsigned)__shfl_xor((int)p2, 32, 64);
  unsigned q3 = (unsigned)__shfl_xor((int)p3, 32, 64);
  u32x4 u;
  u.x = hi ? q2 : p0;
  u.y = hi ? q3 : p1;
  u.z = hi ? p2 : q0;
  u.w = hi ? p3 : q1;
  return FRG(u);
}

#define MM3(ACC, AH, AL, BH, BL) do { \
    ACC = MF(AH,BH,ACC); ACC = MF(AH,BL,ACC); ACC = MF(AL,BH,ACC); } while(0)

// ---------------------------------------------------------------------------
// K1: fully fused. 64 rows/block, 13 waves: waves 0-11 = one expert each,
// wave 12 = gates. In-block gated combine via LDS fp32 accumulator (aliases
// the X tile, which is dead after the expert layers).
// ---------------------------------------------------------------------------
__global__ __launch_bounds__(832, 7) void moe(
    const float* __restrict__ X,
    const float* __restrict__ bt1, const float* __restrict__ bs1,
    const float* __restrict__ bt2, const float* __restrict__ bs2,
    const float* __restrict__ bt3, const float* __restrict__ bs3,
    const float* __restrict__ bg,  const u32x4* __restrict__ fr,
    float* __restrict__ out){
  __shared__ __align__(16) char arena[65536];
  short* Xh = (short*)arena;                       // [64][256] fp16 hi
  short* Xl = (short*)(arena + 32768);             // [64][256] fp16 lo
  float* obuf = (float*)arena;                     // [2][64][67] (after X dies)
  float* gbuf = (float*)(arena + 34304);           // [64][17]
  const int t = threadIdx.x;
  const int grow0 = blockIdx.x*64;

  { // stage X -> hi/lo fp16 LDS, XOR-swizzled by row
    for (int u = t; u < 2048; u += 832){
      int r = u>>5, c8 = u&31;
      const float* xp = X + (size_t)(grow0 + r)*IN_DIM + c8*8;
      f32x4 v0 = *(const f32x4*)xp;
      f32x4 v1 = *(const f32x4*)(xp + 4);
      float vv[8] = {v0.x,v0.y,v0.z,v0.w, v1.x,v1.y,v1.z,v1.w};
      u32x4 uh, ul;
#pragma unroll
      for (int p=0;p<4;p++){
        unsigned short h0,l0,h1,l1;
        split2(vv[2*p],h0,l0); split2(vv[2*p+1],h1,l1);
        uh[p] = (unsigned)h0 | ((unsigned)h1<<16);
        ul[p] = (unsigned)l0 | ((unsigned)l1<<16);
      }
      int addr = r*512 + ((c8*16) ^ ((r&7)<<4));
      *(u32x4*)((char*)Xh + addr) = uh;
      *(u32x4*)((char*)Xl + addr) = ul;
    }
  }
  __syncthreads();                                  // barrier 1: X ready

  const int wave = t>>6, lane = t&63, li = lane&31, hi = lane>>5;
  const int e = wave;
  float gv[32];                                     // wave 12 only: gate values
  f32x16 d00, d01, d10, d11;                        // expert waves: final accs

  if (wave == 12){ // ---- gates: logits^T = Wg^T(padded 32) x X^T, softmax
    f32x16 g0 = Z16(), g1 = Z16();
    const u32x4* AG = fr + U_AG + lane;
#pragma unroll
    for (int kt=0; kt<16; ++kt){
      half8 ah = FRG(AG[(kt*2+0)*64]);
      half8 al = FRG(AG[(kt*2+1)*64]);
      int kb = kt*32 + hi*16;
      half8 xh0 = FRG(lds16(Xh, li,    kb)), xl0 = FRG(lds16(Xl, li,    kb));
      half8 xh1 = FRG(lds16(Xh, li+32, kb)), xl1 = FRG(lds16(Xl, li+32, kb));
      MM3(g0, ah, al, xh0, xl0);
      MM3(g1, ah, al, xh1, xl1);
    }
#pragma unroll
    for (int ct=0; ct<2; ++ct){
      const f32x16& G = ct ? g1 : g0;
      float own[8], par[8];
#pragma unroll
      for (int j=0;j<8;j++) own[j] = G[j] + bg[8*(j>>2) + 4*hi + (j&3)];
#pragma unroll
      for (int j=0;j<8;j++) par[j] = __shfl_xor(own[j], 32, 64);
      float m0 = fmaxf(fmaxf(fmaxf(own[0],own[1]),fmaxf(own[2],own[3])),
                       fmaxf(fmaxf(par[0],par[1]),fmaxf(par[2],par[3])));
      float m1 = fmaxf(fmaxf(fmaxf(own[4],own[5]),fmaxf(own[6],own[7])),
                       fmaxf(fmaxf(par[4],par[5]),fmaxf(par[6],par[7])));
      float eo[8], ep[8];
#pragma unroll
      for (int j=0;j<4;j++){ eo[j] = __expf(own[j]-m0); ep[j] = __expf(par[j]-m0); }
#pragma unroll
      for (int j=4;j<8;j++){ eo[j] = __expf(own[j]-m1); ep[j] = __expf(par[j]-m1); }
      float s0 = eo[0]+eo[1]+eo[2]+eo[3]+ep[0]+ep[1]+ep[2]+ep[3];
      float s1 = eo[4]+eo[5]+eo[6]+eo[7]+ep[4]+ep[5]+ep[6]+ep[7];
      float i0 = 1.f/s0, i1 = 1.f/s1;
#pragma unroll
      for (int j=0;j<4;j++){
        gv[ct*16+j]    = eo[j]*i0;   gv[ct*16+4+j]  = ep[j]*i0;
        gv[ct*16+8+j]  = eo[4+j]*i1; gv[ct*16+12+j] = ep[4+j]*i1;
      }
    }
  } else {
    unsigned opkh[2][2][8], opkl[2][2][8];   // [rt][ct][pair] packed hi/lo fp16
    // -------- layer 1: h1^T = W1^T x X^T  (K=256)
    f32x16 a00=Z16(), a01=Z16(), a10=Z16(), a11=Z16();
    const u32x4* A1 = fr + e*4096 + lane;
#pragma unroll
    for (int kt=0; kt<16; ++kt){
      half8 ah0 = FRG(A1[( kt     *2+0)*64]);
      half8 al0 = FRG(A1[( kt     *2+1)*64]);
      half8 ah1 = FRG(A1[((16+kt) *2+0)*64]);
      half8 al1 = FRG(A1[((16+kt) *2+1)*64]);
      int kb = kt*32 + hi*16;
      half8 xh0 = FRG(lds16(Xh, li,    kb)), xl0 = FRG(lds16(Xl, li,    kb));
      half8 xh1 = FRG(lds16(Xh, li+32, kb)), xl1 = FRG(lds16(Xl, li+32, kb));
      MM3(a00, ah0, al0, xh0, xl0);
      MM3(a01, ah0, al0, xh1, xl1);
      MM3(a10, ah1, al1, xh0, xl0);
      MM3(a11, ah1, al1, xh1, xl1);
    }
    const float* b1 = (e<8)? bt1+e*64 : bs1+(e-8)*64;
    epi12(a00,b1,0,hi,opkh[0][0],opkl[0][0]);
    epi12(a01,b1,0,hi,opkh[0][1],opkl[0][1]);
    epi12(a10,b1,1,hi,opkh[1][0],opkl[1][0]);
    epi12(a11,b1,1,hi,opkh[1][1],opkl[1][1]);
    // -------- layer 2: h2^T = W2^T x h1^T  (K=64, B from registers)
    f32x16 c00=Z16(), c01=Z16(), c10=Z16(), c11=Z16();
    const u32x4* A2 = fr + U_A2 + e*1024 + lane;
#pragma unroll
    for (int kt=0; kt<4; ++kt){
      half8 ah0 = FRG(A2[( kt    *2+0)*64]);
      half8 al0 = FRG(A2[( kt    *2+1)*64]);
      half8 ah1 = FRG(A2[((4+kt) *2+0)*64]);
      half8 al1 = FRG(A2[((4+kt) *2+1)*64]);
      const int rs = kt>>1, kl = kt&1;
      half8 bh0 = bfrag(opkh[rs][0], kl, hi), bl0 = bfrag(opkl[rs][0], kl, hi);
      half8 bh1 = bfrag(opkh[rs][1], kl, hi), bl1 = bfrag(opkl[rs][1], kl, hi);
      MM3(c00, ah0, al0, bh0, bl0);
      MM3(c01, ah0, al0, bh1, bl1);
      MM3(c10, ah1, al1, bh0, bl0);
      MM3(c11, ah1, al1, bh1, bl1);
    }
    const float* b2 = (e<8)? bt2+e*64 : bs2+(e-8)*64;
    epi12(c00,b2,0,hi,opkh[0][0],opkl[0][0]);
    epi12(c01,b2,0,hi,opkh[0][1],opkl[0][1]);
    epi12(c10,b2,1,hi,opkh[1][0],opkl[1][0]);
    epi12(c11,b2,1,hi,opkh[1][1],opkl[1][1]);
    // -------- layer 3: o^T = W3^T x h2^T  (K=64)
    d00=Z16(); d01=Z16(); d10=Z16(); d11=Z16();
    const u32x4* A3 = fr + U_A3 + e*1024 + lane;
#pragma unroll
    for (int kt=0; kt<4; ++kt){
      half8 ah0 = FRG(A3[( kt    *2+0)*64]);
      half8 al0 = FRG(A3[( kt    *2+1)*64]);
      half8 ah1 = FRG(A3[((4+kt) *2+0)*64]);
      half8 al1 = FRG(A3[((4+kt) *2+1)*64]);
      const int rs = kt>>1, kl = kt&1;
      half8 bh0 = bfrag(opkh[rs][0], kl, hi), bl0 = bfrag(opkl[rs][0], kl, hi);
      half8 bh1 = bfrag(opkh[rs][1], kl, hi), bl1 = bfrag(opkl[rs][1], kl, hi);
      MM3(d00, ah0, al0, bh0, bl0);
      MM3(d01, ah0, al0, bh1, bl1);
      MM3(d10, ah1, al1, bh0, bl0);
      MM3(d11, ah1, al1, bh1, bl1);
    }
  }

  __syncthreads();                                  // barrier 2: X dead
  { // zero the output accumulator (aliases X region)
    f32x4 z; z.x=z.y=z.z=z.w=0.f;
    for (int u = t; u < 2144; u += 832) ((f32x4*)obuf)[u] = z;
  }
  if (wave == 12 && hi == 0){                       // publish gates
#pragma unroll
    for (int ct=0; ct<2; ++ct){
      float* gp = gbuf + (size_t)(ct*32+li)*17;
#pragma unroll
      for (int k=0;k<16;k++) gp[k] = gv[ct*16+k];
    }
  }
  __syncthreads();                                  // barrier 3: obuf+gates ready

  if (wave < 12){
    const float* b3p = (e<8)? bt3+e*64 : bs3+(e-8)*64;
    auto combine = [&](const f32x16& D, int rt, int ct){
      int b = ct*32 + li;
      if (e < 8){
        float g = gbuf[b*17 + (e>>2)*8 + (e&3)];
        float* ob = obuf + (size_t)(e>>2)*64*67 + b;
#pragma unroll
        for (int j=0;j<16;j++){
          int o = rt*32 + (j&3) + 8*(j>>2) + 4*hi;
          atomicAdd(ob + o*67, g*(D[j]+b3p[o]));
        }
      } else {
        int s = e-8;
        float g0 = gbuf[b*17 + 4 + s], g1 = gbuf[b*17 + 12 + s];
#pragma unroll
        for (int j=0;j<16;j++){
          int o = rt*32 + (j&3) + 8*(j>>2) + 4*hi;
          float v = D[j]+b3p[o];
          atomicAdd(obuf + o*67 + b,          g0*v);
          atomicAdd(obuf + (64+o)*67 + b,     g1*v);
        }
      }
    };
    combine(d00,0,0); combine(d01,0,1); combine(d10,1,0); combine(d11,1,1);
  }
  __syncthreads();                                  // barrier 4: obuf complete

  // coalesced fp32 store: out[b][t][o]
  for (int v = t; v < 2048; v += 832){
    int b = v>>5, rest = v&31;
    int tt = rest>>4, o4 = (rest&15)*4;
    f32x4 w;
    w.x = obuf[(tt*64+o4+0)*67 + b];
    w.y = obuf[(tt*64+o4+1)*67 + b];
    w.z = obuf[(tt*64+o4+2)*67 + b];
    w.w = obuf[(tt*64+o4+3)*67 + b];
    *(f32x4*)(out + ((size_t)(grow0+b)*2 + tt)*64 + o4) = w;
  }
}

// ---------------------------------------------------------------------------
extern "C" void kernel_launch(void* const* d_in, const int* in_sizes, int n_in,
                              void* d_out, int out_size, void* d_ws, size_t ws_size,
                              hipStream_t stream){
  const float* X   = (const float*)d_in[0];
  const float* Wt1 = (const float*)d_in[1];
  const float* bt1 = (const float*)d_in[2];
  const float* Wt2 = (const float*)d_in[3];
  const float* bt2 = (const float*)d_in[4];
  const float* Wt3 = (const float*)d_in[5];
  const float* bt3 = (const float*)d_in[6];
  const float* Ws1 = (const float*)d_in[7];
  const float* bs1 = (const float*)d_in[8];
  const float* Ws2 = (const float*)d_in[9];
  const float* bs2 = (const float*)d_in[10];
  const float* Ws3 = (const float*)d_in[11];
  const float* bs3 = (const float*)d_in[12];
  const float* Wg  = (const float*)d_in[13];
  const float* bg  = (const float*)d_in[14];

  u32x4* fr = (u32x4*)d_ws;

  hipLaunchKernelGGL(prep, dim3(148), dim3(256), 0, stream,
                     Wt1, Ws1, Wt2, Ws2, Wt3, Ws3, Wg, fr);
  hipLaunchKernelGGL(moe, dim3(B_TOT/64), dim3(832), 0, stream,
                     X, bt1, bs1, bt2, bs2, bt3, bs3, bg, fr, (float*)d_out);
}

// Round 3
// 410.239 us; speedup vs baseline: 3.8504x; 3.8504x over previous
//
#include <hip/hip_runtime.h>
#include <hip/hip_fp16.h>

// ---------------------------------------------------------------------------
// MMoE extract-net, MI355X (gfx950).  R3: barrier-free, LDS-free design.
// fp16 hi/lo split (3-pass MFMA ~= fp32 accuracy), transposed formulation
// (batch = MFMA column).  X pre-split to fp16 hi/lo planes in ws; each
// 64-thread block = one independent work unit (64 rows x 1 expert, or gates).
// Occupancy is VGPR-bound only: launch_bounds(64,3) -> ~12 waves/CU.
// Per-expert outputs -> plane-major fp16 scratch [e][b][64]; comb applies
// softmax gates with fully coalesced reads.
// ---------------------------------------------------------------------------

#define B_TOT   65536
#define IN_DIM  256
#define HD      64
#define NE      12
// ws fragment region layout, in 16-byte units:
//  A1: [e:12][rt:2][kt:16][hl:2][lane:64]   base 0      (12*4096 units)
//  A2: [e:12][rt:2][kt:4 ][hl:2][lane:64]   base 49152  (12*1024)
//  A3: same as A2                            base 61440  (12*1024)
//  AG: [kt:16][hl:2][lane:64]                base 73728  (2048)
#define U_A2 49152
#define U_A3 61440
#define U_AG 73728
#define FRAG_BYTES (75776*16)   // 1,212,416 bytes (divisible by 512)

typedef _Float16 half8  __attribute__((ext_vector_type(8)));
typedef float    f32x16 __attribute__((ext_vector_type(16)));
typedef float    f32x4  __attribute__((ext_vector_type(4)));
typedef unsigned u32x4  __attribute__((ext_vector_type(4)));
typedef unsigned u32x2  __attribute__((ext_vector_type(2)));

__device__ __forceinline__ unsigned short f2h(float x){
  return __builtin_bit_cast(unsigned short, (_Float16)x);
}
__device__ __forceinline__ float h2f(unsigned short u){
  return (float)__builtin_bit_cast(_Float16, u);
}
__device__ __forceinline__ void split2(float x, unsigned short& h, unsigned short& l){
  h = f2h(x); l = f2h(x - h2f(h));
}
__device__ __forceinline__ half8 FRG(u32x4 u){ return __builtin_bit_cast(half8, u); }
__device__ __forceinline__ f32x16 MF(half8 a, half8 b, f32x16 c){
  return __builtin_amdgcn_mfma_f32_32x32x16_f16(a, b, c, 0, 0, 0);
}
__device__ __forceinline__ f32x16 Z16(){
  f32x16 z;
#pragma unroll
  for (int i=0;i<16;i++) z[i]=0.f;
  return z;
}

// ---------------------------------------------------------------------------
// K0: pre-split weights into hi/lo fp16 MFMA A-fragment layout.
// A-frag (32x32x16): lane holds row=(lane&31), k=(lane>>5)*8 + j, j=0..7.
// (verified in R1/R2)
// ---------------------------------------------------------------------------
__global__ __launch_bounds__(256) void prep(
    const float* __restrict__ Wt1, const float* __restrict__ Ws1,
    const float* __restrict__ Wt2, const float* __restrict__ Ws2,
    const float* __restrict__ Wt3, const float* __restrict__ Ws3,
    const float* __restrict__ Wg,  u32x4* __restrict__ fr){
  int id = blockIdx.x*256 + threadIdx.x;
  if (id >= 37888) return;
  int lane = id & 63;
  int kq   = lane >> 5;
  int row  = lane & 31;
  float v[8];
  unsigned ubase;
  if (id < 24576){                                   // A1 = W1^T  [h][k=in]
    int r = id >> 6; int kt = r & 15; int rt = (r>>4)&1; int e = r>>5;
    const float* W = (e<8) ? (Wt1 + (size_t)e*(IN_DIM*HD))
                           : (Ws1 + (size_t)(e-8)*(IN_DIM*HD));
    int h = rt*32 + row;
#pragma unroll
    for (int j=0;j<8;j++){ int k = kt*16 + kq*8 + j; v[j] = W[k*HD + h]; }
    ubase = (unsigned)(e*4096 + ((rt*16+kt)*2)*64 + lane);
  } else if (id < 30720){                            // A2 = W2^T  [h2][k=h1]
    int r = (id-24576) >> 6; int kt = r & 3; int rt = (r>>2)&1; int e = r>>3;
    const float* W = (e<8) ? (Wt2 + (size_t)e*(HD*HD))
                           : (Ws2 + (size_t)(e-8)*(HD*HD));
    int h = rt*32 + row;
#pragma unroll
    for (int j=0;j<8;j++){ int k = kt*16 + kq*8 + j; v[j] = W[k*HD + h]; }
    ubase = (unsigned)(U_A2 + e*1024 + ((rt*4+kt)*2)*64 + lane);
  } else if (id < 36864){                            // A3 = W3^T  [o][k=h2]
    int r = (id-30720) >> 6; int kt = r & 3; int rt = (r>>2)&1; int e = r>>3;
    const float* W = (e<8) ? (Wt3 + (size_t)e*(HD*HD))
                           : (Ws3 + (size_t)(e-8)*(HD*HD));
    int h = rt*32 + row;
#pragma unroll
    for (int j=0;j<8;j++){ int k = kt*16 + kq*8 + j; v[j] = W[k*HD + h]; }
    ubase = (unsigned)(U_A3 + e*1024 + ((rt*4+kt)*2)*64 + lane);
  } else {                                           // AG = Wg^T padded to 32 rows
    int r = (id-36864) >> 6; int kt = r;
    int g = row;
#pragma unroll
    for (int j=0;j<8;j++){
      int k = kt*16 + kq*8 + j;
      v[j] = (g < 16) ? Wg[(size_t)(g>>3)*(IN_DIM*8) + k*8 + (g&7)] : 0.f;
    }
    ubase = (unsigned)(U_AG + (kt*2)*64 + lane);
  }
  u32x4 uh, ul;
#pragma unroll
  for (int p=0;p<4;p++){
    unsigned short h0,l0,h1,l1;
    split2(v[2*p],h0,l0); split2(v[2*p+1],h1,l1);
    uh[p] = (unsigned)h0 | ((unsigned)h1<<16);
    ul[p] = (unsigned)l0 | ((unsigned)l1<<16);
  }
  fr[ubase]     = uh;
  fr[ubase+64]  = ul;
}

// ---------------------------------------------------------------------------
// K0b: split X rows -> fp16 hi/lo planes [b][k] (row stride 512 B each).
// ---------------------------------------------------------------------------
__global__ __launch_bounds__(256) void xsplit(
    const float* __restrict__ X, u32x2* __restrict__ xh,
    u32x2* __restrict__ xl, int n4){
  int tid = blockIdx.x*256 + threadIdx.x;
  if (tid >= n4) return;
  f32x4 v = ((const f32x4*)X)[tid];
  float vv[4] = {v.x, v.y, v.z, v.w};
  u32x2 uh, ul;
#pragma unroll
  for (int p=0;p<2;p++){
    unsigned short h0,l0,h1,l1;
    split2(vv[2*p],h0,l0); split2(vv[2*p+1],h1,l1);
    uh[p] = (unsigned)h0 | ((unsigned)h1<<16);
    ul[p] = (unsigned)l0 | ((unsigned)l1<<16);
  }
  xh[tid] = uh;
  xl[tid] = ul;
}

// ---------------------------------------------------------------------------
// epilogue (layers 1/2): bias + relu + fp16 hi/lo split, packed as u32 pairs.
// C/D layout: col=lane&31, row=(j&3)+8*(j>>2)+4*hi  (+32*rt)  (verified)
__device__ __forceinline__ void epi12(const f32x16& A, const float* bp, int rt, int hi,
                                      unsigned* oh, unsigned* ol){
#pragma unroll
  for (int p=0;p<8;p++){
    const int j0=2*p, j1=2*p+1;
    float v0 = A[j0] + bp[rt*32 + 8*(j0>>2) + 4*hi + (j0&3)];
    float v1 = A[j1] + bp[rt*32 + 8*(j1>>2) + 4*hi + (j1&3)];
    v0 = fmaxf(v0, 0.f); v1 = fmaxf(v1, 0.f);
    unsigned short h0,l0,h1,l1;
    split2(v0,h0,l0); split2(v1,h1,l1);
    oh[p] = (unsigned)h0 | ((unsigned)h1<<16);
    ol[p] = (unsigned)l0 | ((unsigned)l1<<16);
  }
}

// Build B-frag (k=16kt+8*hi + 0..7 of h-dim) from packed C/D pairs via
// half-wave exchange. pk = 8 u32 pairs of one (rt,ct) tile; kl = kt&1. (verified)
__device__ __forceinline__ half8 bfrag(const unsigned* pk, int kl, int hi){
  unsigned p0 = pk[4*kl+0], p1 = pk[4*kl+1], p2 = pk[4*kl+2], p3 = pk[4*kl+3];
  unsigned q0 = (unsigned)__shfl_xor((int)p0, 32, 64);
  unsigned q1 = (unsigned)__shfl_xor((int)p1, 32, 64);
  unsigned q2 = (unsigned)__shfl_xor((int)p2, 32, 64);
  unsigned q3 = (unsigned)__shfl_xor((int)p3, 32, 64);
  u32x4 u;
  u.x = hi ? q2 : p0;
  u.y = hi ? q3 : p1;
  u.z = hi ? p2 : q0;
  u.w = hi ? p3 : q1;
  return FRG(u);
}

// layer-3 epilogue: bias, fp16, assemble o-octets; each lane stores one
// contiguous 32B chunk to plane-major scratch [e][b][64] fp16. (verified logic)
__device__ __forceinline__ void epi3(const f32x16& A, const float* bp, int rt, int ct,
                                     int hi, int li, size_t ebase, char* osc){
  unsigned f[8];
#pragma unroll
  for (int p=0;p<8;p++){
    const int j0=2*p, j1=2*p+1;
    float v0 = A[j0] + bp[rt*32 + 8*(j0>>2) + 4*hi + (j0&3)];
    float v1 = A[j1] + bp[rt*32 + 8*(j1>>2) + 4*hi + (j1&3)];
    f[p] = (unsigned)f2h(v0) | ((unsigned)f2h(v1)<<16);
  }
  unsigned g[8];
#pragma unroll
  for (int p=0;p<8;p++) g[p] = (unsigned)__shfl_xor((int)f[p], 32, 64);
  char* ob = osc + (ebase + (size_t)(ct*32 + li))*128 + rt*64;
#pragma unroll
  for (int q=0;q<4;q++){
    u32x4 w;
    w.x = hi ? g[2*q]   : f[2*q];
    w.y = hi ? g[2*q+1] : f[2*q+1];
    w.z = hi ? f[2*q]   : g[2*q];
    w.w = hi ? f[2*q+1] : g[2*q+1];
    if ((q>>1) == hi) *(u32x4*)(ob + q*16) = w;
  }
}

#define MM3(ACC, AH, AL, BH, BL) do { \
    ACC = MF(AH,BH,ACC); ACC = MF(AH,BL,ACC); ACC = MF(AL,BH,ACC); } while(0)

// ---------------------------------------------------------------------------
// K1: one 64-thread block = one unit. Units e-major: blockIdx = e*G + g,
// e<12: expert e for 64-row group g; e==12: gate unit for group g.
// No LDS, no barriers. B-fragments read straight from xh/xl planes.
// ---------------------------------------------------------------------------
__global__ __launch_bounds__(64,3) void moe1(
    const char* __restrict__ xh, const char* __restrict__ xl,
    const float* __restrict__ bt1, const float* __restrict__ bs1,
    const float* __restrict__ bt2, const float* __restrict__ bs2,
    const float* __restrict__ bt3, const float* __restrict__ bs3,
    const float* __restrict__ bg,  const u32x4* __restrict__ fr,
    float* __restrict__ gout, char* __restrict__ osc, int G, int Crows){
  const int e = blockIdx.x / G;
  const int g = blockIdx.x - e*G;
  const int lane = threadIdx.x, li = lane&31, hi = lane>>5;

  // per-ct, per-plane base pointers for X B-fragments (imm offset = kt*32)
  const char* xh0p = xh + (size_t)(g*64 +      li)*512 + hi*16;
  const char* xh1p = xh + (size_t)(g*64 + 32 + li)*512 + hi*16;
  const char* xl0p = xl + (size_t)(g*64 +      li)*512 + hi*16;
  const char* xl1p = xl + (size_t)(g*64 + 32 + li)*512 + hi*16;

  if (e == 12){  // ---- gate unit: logits^T = Wg^T(pad32) x X^T, softmax ----
    f32x16 g0 = Z16(), g1 = Z16();
    const u32x4* AG = fr + U_AG + lane;
#pragma unroll
    for (int kt=0; kt<16; ++kt){
      half8 ah = FRG(AG[(kt*2+0)*64]);
      half8 al = FRG(AG[(kt*2+1)*64]);
      half8 xh0 = FRG(*(const u32x4*)(xh0p + kt*32));
      half8 xl0v= FRG(*(const u32x4*)(xl0p + kt*32));
      half8 xh1 = FRG(*(const u32x4*)(xh1p + kt*32));
      half8 xl1v= FRG(*(const u32x4*)(xl1p + kt*32));
      MM3(g0, ah, al, xh0, xl0v);
      MM3(g1, ah, al, xh1, xl1v);
    }
#pragma unroll
    for (int ct=0; ct<2; ++ct){
      const f32x16& Gc = ct ? g1 : g0;
      float own[8], par[8];
#pragma unroll
      for (int j=0;j<8;j++) own[j] = Gc[j] + bg[8*(j>>2) + 4*hi + (j&3)];
#pragma unroll
      for (int j=0;j<8;j++) par[j] = __shfl_xor(own[j], 32, 64);
      float m0 = fmaxf(fmaxf(fmaxf(own[0],own[1]),fmaxf(own[2],own[3])),
                       fmaxf(fmaxf(par[0],par[1]),fmaxf(par[2],par[3])));
      float m1 = fmaxf(fmaxf(fmaxf(own[4],own[5]),fmaxf(own[6],own[7])),
                       fmaxf(fmaxf(par[4],par[5]),fmaxf(par[6],par[7])));
      float eo[8], ep[8];
#pragma unroll
      for (int j=0;j<4;j++){ eo[j] = __expf(own[j]-m0); ep[j] = __expf(par[j]-m0); }
#pragma unroll
      for (int j=4;j<8;j++){ eo[j] = __expf(own[j]-m1); ep[j] = __expf(par[j]-m1); }
      float s0 = eo[0]+eo[1]+eo[2]+eo[3]+ep[0]+ep[1]+ep[2]+ep[3];
      float s1 = eo[4]+eo[5]+eo[6]+eo[7]+ep[4]+ep[5]+ep[6]+ep[7];
      float i0 = 1.f/s0, i1 = 1.f/s1;
      if (hi == 0){
        float* gp = gout + (size_t)(g*64 + ct*32 + li)*16;
        f32x4 w;
        w.x=eo[0]*i0; w.y=eo[1]*i0; w.z=eo[2]*i0; w.w=eo[3]*i0; ((f32x4*)gp)[0]=w;
        w.x=ep[0]*i0; w.y=ep[1]*i0; w.z=ep[2]*i0; w.w=ep[3]*i0; ((f32x4*)gp)[1]=w;
        w.x=eo[4]*i1; w.y=eo[5]*i1; w.z=eo[6]*i1; w.w=eo[7]*i1; ((f32x4*)gp)[2]=w;
        w.x=ep[4]*i1; w.y=ep[5]*i1; w.z=ep[6]*i1; w.w=ep[7]*i1; ((f32x4*)gp)[3]=w;
      }
    }
    return;
  }

  // ---- expert unit ----
  unsigned o1h[2][2][8], o1l[2][2][8];   // h1 packed [rt][ct][pair]
  // layer 1: h1^T = W1^T x X^T  (K=256)
  {
    f32x16 a00=Z16(), a01=Z16(), a10=Z16(), a11=Z16();
    const u32x4* A1 = fr + e*4096 + lane;
#pragma unroll
    for (int kt=0; kt<16; ++kt){
      half8 ah0 = FRG(A1[( kt     *2+0)*64]);
      half8 al0 = FRG(A1[( kt     *2+1)*64]);
      half8 ah1 = FRG(A1[((16+kt) *2+0)*64]);
      half8 al1 = FRG(A1[((16+kt) *2+1)*64]);
      half8 xh0 = FRG(*(const u32x4*)(xh0p + kt*32));
      half8 xl0v= FRG(*(const u32x4*)(xl0p + kt*32));
      half8 xh1 = FRG(*(const u32x4*)(xh1p + kt*32));
      half8 xl1v= FRG(*(const u32x4*)(xl1p + kt*32));
      MM3(a00, ah0, al0, xh0, xl0v);
      MM3(a01, ah0, al0, xh1, xl1v);
      MM3(a10, ah1, al1, xh0, xl0v);
      MM3(a11, ah1, al1, xh1, xl1v);
    }
    const float* b1 = (e<8)? bt1+e*64 : bs1+(e-8)*64;
    epi12(a00,b1,0,hi,o1h[0][0],o1l[0][0]);
    epi12(a01,b1,0,hi,o1h[0][1],o1l[0][1]);
    epi12(a10,b1,1,hi,o1h[1][0],o1l[1][0]);
    epi12(a11,b1,1,hi,o1h[1][1],o1l[1][1]);
  }
  const float* b2 = (e<8)? bt2+e*64 : bs2+(e-8)*64;
  const float* b3 = (e<8)? bt3+e*64 : bs3+(e-8)*64;
  const size_t ebase = (size_t)e*Crows + (size_t)g*64;

  // layers 2+3, per-ct pass (halves opk live range -> lower VGPR peak)
#pragma unroll
  for (int ct=0; ct<2; ++ct){
    unsigned o2h[2][8], o2l[2][8];       // h2 packed [rt][pair], this ct
    {
      f32x16 c0=Z16(), c1=Z16();
      const u32x4* A2 = fr + U_A2 + e*1024 + lane;
#pragma unroll
      for (int kt=0; kt<4; ++kt){
        half8 ah0 = FRG(A2[( kt    *2+0)*64]);
        half8 al0 = FRG(A2[( kt    *2+1)*64]);
        half8 ah1 = FRG(A2[((4+kt) *2+0)*64]);
        half8 al1 = FRG(A2[((4+kt) *2+1)*64]);
        const int rs = kt>>1, kl = kt&1;
        half8 bh = bfrag(o1h[rs][ct], kl, hi), bl = bfrag(o1l[rs][ct], kl, hi);
        MM3(c0, ah0, al0, bh, bl);
        MM3(c1, ah1, al1, bh, bl);
      }
      epi12(c0,b2,0,hi,o2h[0],o2l[0]);
      epi12(c1,b2,1,hi,o2h[1],o2l[1]);
    }
    {
      f32x16 d0=Z16(), d1=Z16();
      const u32x4* A3 = fr + U_A3 + e*1024 + lane;
#pragma unroll
      for (int kt=0; kt<4; ++kt){
        half8 ah0 = FRG(A3[( kt    *2+0)*64]);
        half8 al0 = FRG(A3[( kt    *2+1)*64]);
        half8 ah1 = FRG(A3[((4+kt) *2+0)*64]);
        half8 al1 = FRG(A3[((4+kt) *2+1)*64]);
        const int rs = kt>>1, kl = kt&1;
        half8 bh = bfrag(o2h[rs], kl, hi), bl = bfrag(o2l[rs], kl, hi);
        MM3(d0, ah0, al0, bh, bl);
        MM3(d1, ah1, al1, bh, bl);
      }
      epi3(d0,b3,0,ct,hi,li,ebase,osc);
      epi3(d1,b3,1,ct,hi,li,ebase,osc);
    }
  }
}

// ---------------------------------------------------------------------------
// K2: gated combine.  out[b][t][o] = sum_e gate(b,t,e) * o_e[b][o]
// osc plane-major [e][b][64] fp16 -> fully coalesced reads.
// ---------------------------------------------------------------------------
__device__ __forceinline__ float2 uph(unsigned u){
  __half2 h = __builtin_bit_cast(__half2, u);
  return __half22float2(h);
}
__global__ __launch_bounds__(256) void comb(
    const char* __restrict__ osc, const float* __restrict__ g,
    float* __restrict__ out, int Crows, int crow0){
  int tid = blockIdx.x*256 + threadIdx.x;
  if (tid >= Crows*16) return;
  int b = tid>>4, o4 = tid&15;
  const float* gp = g + (size_t)b*16;
  float s0[4] = {0.f,0.f,0.f,0.f}, s1[4] = {0.f,0.f,0.f,0.f};
#pragma unroll
  for (int e=0;e<12;e++){
    const u32x2 u = *(const u32x2*)(osc + ((size_t)e*Crows + b)*128 + o4*8);
    float2 f0 = uph(u.x), f1 = uph(u.y);
    float v[4] = {f0.x, f0.y, f1.x, f1.y};
    float w0 = (e<4) ? gp[e] : (e>=8 ? gp[e-4] : 0.f);
    float w1 = (e<4) ? 0.f  : (e<8 ? gp[4+e] : gp[e+4]);
#pragma unroll
    for (int i=0;i<4;i++){ s0[i] += w0*v[i]; s1[i] += w1*v[i]; }
  }
  float* op = out + ((size_t)(crow0+b))*128 + o4*4;
  f32x4 w0v; w0v.x=s0[0]; w0v.y=s0[1]; w0v.z=s0[2]; w0v.w=s0[3];
  f32x4 w1v; w1v.x=s1[0]; w1v.y=s1[1]; w1v.z=s1[2]; w1v.w=s1[3];
  *(f32x4*)op        = w0v;
  *(f32x4*)(op + 64) = w1v;
}

// ---------------------------------------------------------------------------
extern "C" void kernel_launch(void* const* d_in, const int* in_sizes, int n_in,
                              void* d_out, int out_size, void* d_ws, size_t ws_size,
                              hipStream_t stream){
  const float* X   = (const float*)d_in[0];
  const float* Wt1 = (const float*)d_in[1];
  const float* bt1 = (const float*)d_in[2];
  const float* Wt2 = (const float*)d_in[3];
  const float* bt2 = (const float*)d_in[4];
  const float* Wt3 = (const float*)d_in[5];
  const float* bt3 = (const float*)d_in[6];
  const float* Ws1 = (const float*)d_in[7];
  const float* bs1 = (const float*)d_in[8];
  const float* Ws2 = (const float*)d_in[9];
  const float* bs2 = (const float*)d_in[10];
  const float* Ws3 = (const float*)d_in[11];
  const float* bs3 = (const float*)d_in[12];
  const float* Wg  = (const float*)d_in[13];
  const float* bg  = (const float*)d_in[14];

  char* ws = (char*)d_ws;
  u32x4* fr = (u32x4*)ws;

  // per-row scratch: xh 512 + xl 512 + osc 1536 + gout 64 = 2624 B
  int C = B_TOT;
  while (C > 64 && (size_t)FRAG_BYTES + (size_t)C*2624 > ws_size) C >>= 1;
  char* xh  = ws + FRAG_BYTES;
  char* xl  = xh + (size_t)C*512;
  char* osc = xl + (size_t)C*512;
  float* gts = (float*)(osc + (size_t)C*1536);
  const int G = C/64;

  hipLaunchKernelGGL(prep, dim3(148), dim3(256), 0, stream,
                     Wt1, Ws1, Wt2, Ws2, Wt3, Ws3, Wg, fr);
  for (int r0 = 0; r0 < B_TOT; r0 += C){
    hipLaunchKernelGGL(xsplit, dim3(C/4), dim3(256), 0, stream,
                       X + (size_t)r0*IN_DIM, (u32x2*)xh, (u32x2*)xl, C*64);
    hipLaunchKernelGGL(moe1, dim3(13*G), dim3(64), 0, stream,
                       xh, xl, bt1, bs1, bt2, bs2, bt3, bs3, bg, fr,
                       gts, osc, G, C);
    hipLaunchKernelGGL(comb, dim3(C/16), dim3(256), 0, stream,
                       osc, gts, (float*)d_out, C, r0);
  }
}